// Round 13
// baseline (38.540 us; speedup 1.0000x reference)
//
#include <hip/hip_runtime.h>
#include <math.h>

#define NKEYS 8192
#define NBINS 128
#define NFREQ 64
#define NKER  3
#define HEADD 128

// Fourier expansion: e^{k(cos d - 1)} = e^-k [I0(k) + 2 sum_m Im(k) cos(m d)]
// kappa <= 1, M=3 (verified R11/R12: absmax 0.03125 vs threshold 0.152).
#define MHARM 3
#define NCH   7                    // {1, cos m, sin m}, m=1..3
#define KDIM  (NCH * NFREQ)        // 448
#define KSTEPS (KDIM / 32)         // 14 MFMA K-steps

// Fragment-order k-mapping (16x16x32 f16 MFMA, verified rounds 3-12):
//   k_global = kt*32 + q*8 + j  (q = lane>>4, j = 0..7)
//   (ch, f) <-> kt = ch*2 + (f>>5), q = (f>>3)&3, j = f&7   (bijective)

#define BM 32                      // rows per block (2 chunks of 16)
#define GT 256                     // 4 waves; wave w -> 16 cols

typedef _Float16 f16x8 __attribute__((ext_vector_type(8)));
typedef float    f32x4 __attribute__((ext_vector_type(4)));

// ---------------------------------------------------------------------------
// Single fused kernel, spill-proof schedule:
//   phase 1: A-features -> LDS in fragment order (28,672 B)
//   barrier
//   phase 2: per HALF: compute bf[7] B-fragments (transient, 28 VGPR),
//            immediately consume with 7 kt x 2 row-chunk MFMAs, discard.
// No operand array is live across the barrier (R11's spill trigger).
// Grid 512 = 256 rowgroups x 2 col-halves -> 2 blocks/CU, 2 waves/SIMD:
// one block's B-VALU overlaps the other's MFMA/ds phase.
// ---------------------------------------------------------------------------
__global__ __launch_bounds__(GT, 2) void fused_all(
    const float* __restrict__ K,
    const float* __restrict__ refang,
    const float* __restrict__ mu,
    const float* __restrict__ kappa,
    const float* __restrict__ weight,
    const float* __restrict__ bias,
    float* __restrict__ out)
{
    __shared__ __align__(16) _Float16 Afrag[2 * KSTEPS * 512];   // 28,672 B

    const int tid  = threadIdx.x;
    const int bid  = blockIdx.x;
    const int row0 = (bid >> 1) * BM;
    const int cblk = bid & 1;                    // which 64-col half

    // ---------------- A prologue: 256 octet jobs, 1 per thread -------------
    {
        const int n  = tid >> 3;                 // row 0..31
        const int oc = tid & 7;                  // freq octet 0..7
        const int qa = oc & 3, half = oc >> 2;
        const int chunk = n >> 4, lcn = n & 15;

        const float4* ldp = (const float4*)(K + (size_t)(row0 + n) * HEADD + oc * 16);
        const float4 p0 = ldp[0], p1 = ldp[1], p2 = ldp[2], p3 = ldp[3];
        const float xs[8] = {p0.x, p0.z, p1.x, p1.z, p2.x, p2.z, p3.x, p3.z};
        const float ys[8] = {p0.y, p0.w, p1.y, p1.w, p2.y, p2.w, p3.y, p3.w};

        float mag[8], c1[8], cc[8], sc[8], cp[8], sp[8];
        f16x8 v;
        #pragma unroll
        for (int i = 0; i < 8; ++i) {
            const float m2 = xs[i] * xs[i] + ys[i] * ys[i];
            const float ri = (m2 > 0.f) ? rsqrtf(m2) : 0.f;
            mag[i] = m2 * ri;
            c1[i] = xs[i] * ri;
            const float s1 = ys[i] * ri;
            cp[i] = 1.f; sp[i] = 0.f; cc[i] = c1[i]; sc[i] = s1;
            v[i] = (_Float16)mag[i];
        }
        // kt = ch*2 + half -> halfs offset ch*1024 + half*512
        _Float16* base = Afrag + chunk * (KSTEPS * 512) + half * 512
                               + (qa * 16 + lcn) * 8;
        *(f16x8*)base = v;                                   // ch 0
        #pragma unroll
        for (int m = 1; m <= MHARM; ++m) {
            f16x8 vc, vs;
            #pragma unroll
            for (int i = 0; i < 8; ++i) {
                vc[i] = (_Float16)(mag[i] * cc[i]);
                vs[i] = (_Float16)(mag[i] * sc[i]);
                const float cn = fmaf(2.f * c1[i], cc[i], -cp[i]);
                const float sn = fmaf(2.f * c1[i], sc[i], -sp[i]);
                cp[i] = cc[i]; sp[i] = sc[i]; cc[i] = cn; sc[i] = sn;
            }
            *(f16x8*)(base + (2 * m - 1) * 1024) = vc;
            *(f16x8*)(base + (2 * m) * 1024)     = vs;
        }
    }

    __syncthreads();

    // ---------------- per-half B-compute + MFMA (no cross-barrier array) ---
    const int lane = tid & 63, wave = tid >> 6;
    const int q = lane >> 4, lc = lane & 15;
    const int g = cblk * 4 + wave;               // col group 0..7
    const int bin = g * 16 + lc;

    const f16x8* ap = (const f16x8*)Afrag + lane;       // lane*16B, conflict-free
    f32x4 acc0 = {0.f, 0.f, 0.f, 0.f};
    f32x4 acc1 = {0.f, 0.f, 0.f, 0.f};

    #pragma unroll
    for (int half = 0; half < 2; ++half) {
        const int fb = half * 32 + q * 8;        // this lane's 8 freqs
        f16x8 bf[7];                             // transient: 28 VGPR

        #pragma unroll
        for (int jq = 0; jq < 2; ++jq) {         // two quads of 4 freqs
            // 12 consecutive floats per array = 4 freqs x 3 kernels, 16B-aligned
            const size_t off = ((size_t)bin * NFREQ + fb + jq * 4) * NKER;
            float4 m4[3], k4[3], w4[3];
            #pragma unroll
            for (int i = 0; i < 3; ++i) {
                m4[i] = ((const float4*)(mu + off))[i];
                k4[i] = ((const float4*)(kappa + off))[i];
                w4[i] = ((const float4*)(weight + off))[i];
            }
            const float* mv = (const float*)m4;
            const float* kv = (const float*)k4;
            const float* wv = (const float*)w4;

            #pragma unroll
            for (int jj = 0; jj < 4; ++jj) {
                const int j = jq * 4 + jj;
                const float rf = refang[fb + j];
                float ach[NCH];
                #pragma unroll
                for (int c = 0; c < NCH; ++c) ach[c] = 0.f;

                #pragma unroll
                for (int k = 0; k < NKER; ++k) {
                    const float me  = mv[3 * jj + k] + rf;
                    const float kap = kv[3 * jj + k];
                    const float w   = wv[3 * jj + k];
                    const float wek = w * __expf(-kap);
                    float s1, c1;
                    __sincosf(me, &s1, &c1);
                    const float h = 0.5f * kap, h2 = h * h;

                    float Im[MHARM + 1];
                    float tm = 1.f;               // h^m / m!
                    #pragma unroll
                    for (int m = 0; m <= MHARM; ++m) {
                        float t = tm, s = tm;
                        #pragma unroll
                        for (int u = 1; u <= 4; ++u) { t *= h2 / (float)(u * (m + u)); s += t; }
                        Im[m] = s;
                        tm *= h / (float)(m + 1);
                    }

                    ach[0] = fmaf(wek, Im[0], ach[0]);
                    float cp = 1.f, sp = 0.f, cc = c1, sc = s1;
                    #pragma unroll
                    for (int m = 1; m <= MHARM; ++m) {
                        const float gm = 2.f * wek * Im[m];
                        ach[2 * m - 1] = fmaf(gm, cc, ach[2 * m - 1]);
                        ach[2 * m]     = fmaf(gm, sc, ach[2 * m]);
                        const float cn = fmaf(2.f * c1, cc, -cp);
                        const float sn = fmaf(2.f * c1, sc, -sp);
                        cp = cc; sp = sc; cc = cn; sc = sn;
                    }
                }
                #pragma unroll
                for (int c = 0; c < NCH; ++c) bf[c][j] = (_Float16)ach[c];
            }
        }

        // consume immediately: 7 kts x 2 row-chunks
        #pragma unroll
        for (int c = 0; c < NCH; ++c) {
            const int kt = c * 2 + half;
            const f16x8 a0 = ap[kt * 64];
            const f16x8 a1 = ap[KSTEPS * 64 + kt * 64];
            acc0 = __builtin_amdgcn_mfma_f32_16x16x32_f16(a0, bf[c], acc0, 0, 0, 0);
            acc1 = __builtin_amdgcn_mfma_f32_16x16x32_f16(a1, bf[c], acc1, 0, 0, 0);
        }
    }

    // C/D layout: col = lane&15, row = (lane>>4)*4 + reg
    const int col = g * 16 + lc;
    const float bb = bias[col];
    #pragma unroll
    for (int jj = 0; jj < 4; ++jj) {
        out[(size_t)(row0 + q * 4 + jj) * NBINS + col]      = acc0[jj] + bb;
        out[(size_t)(row0 + 16 + q * 4 + jj) * NBINS + col] = acc1[jj] + bb;
    }
}

// ---------------------------------------------------------------------------
extern "C" void kernel_launch(void* const* d_in, const int* in_sizes, int n_in,
                              void* d_out, int out_size, void* d_ws, size_t ws_size,
                              hipStream_t stream) {
    const float* K      = (const float*)d_in[0];
    const float* refang = (const float*)d_in[1];
    const float* mu     = (const float*)d_in[2];
    const float* kappa  = (const float*)d_in[3];
    const float* weight = (const float*)d_in[4];
    const float* bias   = (const float*)d_in[5];
    float* out = (float*)d_out;

    (void)d_ws; (void)ws_size; (void)in_sizes; (void)n_in; (void)out_size;

    fused_all<<<(NKEYS / BM) * 2, GT, 0, stream>>>(
        K, refang, mu, kappa, weight, bias, out);
}

// Round 14
// 24.310 us; speedup vs baseline: 1.5854x; 1.5854x over previous
//
#include <hip/hip_runtime.h>
#include <math.h>

#define NKEYS 8192
#define NBINS 128
#define NFREQ 64
#define NKER  3
#define HEADD 128

// Fourier expansion: e^{k(cos d - 1)} = e^-k [I0(k) + 2 sum_m Im(k) cos(m d)]
// kappa <= 1, M=3 (verified R11-R13: absmax 0.03125 vs threshold 0.152).
#define MHARM 3
#define NCH   7                    // {1, cos m, sin m}, m=1..3
#define KDIM  (NCH * NFREQ)        // 448
#define KSTEPS (KDIM / 32)         // 14 MFMA K-steps

// Fragment-order k-mapping (16x16x32 f16 MFMA, verified rounds 3-13):
//   k_global = kt*32 + q*8 + j  (q = lane>>4, j = 0..7)
//   (ch, f) <-> kt = ch*2 + (f>>5), q = (f>>3)&3, j = f&7   (bijective)
// LDS slot swizzle (kills 8-way write conflicts, read stays conflict-free):
//   slot s (0..63) stored at s ^ ((s>>3)&7)  -- bijective within each kt block.
#define SWZ(s) ((s) ^ (((s) >> 3) & 7))

#define BM 64                      // rows per block (4 chunks of 16) -- R6 champion
#define GT 256                     // 4 waves; wave w -> 16 cols

typedef _Float16 f16x8 __attribute__((ext_vector_type(8)));
typedef float    f32x4 __attribute__((ext_vector_type(4)));

// ---------------------------------------------------------------------------
// Single fused kernel (R6 champion structure, M=3, swizzled LDS):
//  - A-features -> LDS in fragment order (57,344 B)
//  - B-coefficients computed per lane IN REGISTERS (1 col x 16 freqs),
//    BEFORE the barrier (R13 showed interleaving them after trips the
//    allocator into a 60-VGPR spill mode)
//  - 14 K-steps x 4 row-chunks of 16x16x32 f16 MFMA, B held in VGPRs
// Grid 256 = 128 rowgroups x 2 col-halves -> 1 block/CU.
// ---------------------------------------------------------------------------
__global__ __launch_bounds__(GT, 2) void fused_all(
    const float* __restrict__ K,
    const float* __restrict__ refang,
    const float* __restrict__ mu,
    const float* __restrict__ kappa,
    const float* __restrict__ weight,
    const float* __restrict__ bias,
    float* __restrict__ out)
{
    __shared__ __align__(16) _Float16 Afrag[4 * KSTEPS * 512];   // 57,344 B

    const int tid  = threadIdx.x;
    const int bid  = blockIdx.x;
    const int row0 = (bid >> 1) * BM;
    const int cblk = bid & 1;                    // which 64-col half

    // ---------------- A prologue: 512 octet jobs, 2 per thread -------------
    #pragma unroll
    for (int it = 0; it < 2; ++it) {
        const int o  = tid + it * GT;
        const int n  = o >> 3;                   // row 0..63
        const int oc = o & 7;                    // freq octet 0..7
        const int qa = oc & 3, half = oc >> 2;
        const int chunk = n >> 4, lcn = n & 15;

        const float4* ldp = (const float4*)(K + (size_t)(row0 + n) * HEADD + oc * 16);
        const float4 p0 = ldp[0], p1 = ldp[1], p2 = ldp[2], p3 = ldp[3];
        const float xs[8] = {p0.x, p0.z, p1.x, p1.z, p2.x, p2.z, p3.x, p3.z};
        const float ys[8] = {p0.y, p0.w, p1.y, p1.w, p2.y, p2.w, p3.y, p3.w};

        float mag[8], c1[8], cc[8], sc[8], cp[8], sp[8];
        f16x8 v;
        #pragma unroll
        for (int i = 0; i < 8; ++i) {
            const float m2 = xs[i] * xs[i] + ys[i] * ys[i];
            const float ri = (m2 > 0.f) ? rsqrtf(m2) : 0.f;
            mag[i] = m2 * ri;
            c1[i] = xs[i] * ri;
            const float s1 = ys[i] * ri;
            cp[i] = 1.f; sp[i] = 0.f; cc[i] = c1[i]; sc[i] = s1;
            v[i] = (_Float16)mag[i];
        }
        const int slot = SWZ(qa * 16 + lcn);     // swizzled slot within kt block
        // kt = ch*2 + half -> halfs offset ch*1024 + half*512
        _Float16* base = Afrag + chunk * (KSTEPS * 512) + half * 512 + slot * 8;
        *(f16x8*)base = v;                                   // ch 0
        #pragma unroll
        for (int m = 1; m <= MHARM; ++m) {
            f16x8 vc, vs;
            #pragma unroll
            for (int i = 0; i < 8; ++i) {
                vc[i] = (_Float16)(mag[i] * cc[i]);
                vs[i] = (_Float16)(mag[i] * sc[i]);
                const float cn = fmaf(2.f * c1[i], cc[i], -cp[i]);
                const float sn = fmaf(2.f * c1[i], sc[i], -sp[i]);
                cp[i] = cc[i]; sp[i] = sc[i]; cc[i] = cn; sc[i] = sn;
            }
            *(f16x8*)(base + (2 * m - 1) * 1024) = vc;
            *(f16x8*)(base + (2 * m) * 1024)     = vs;
        }
    }

    // ---------------- B coefficients in registers (1 col x 16 freqs) -------
    const int lane = tid & 63, wave = tid >> 6;
    const int q = lane >> 4, lc = lane & 15;
    const int g = cblk * 4 + wave;               // col group 0..7
    const int bin = g * 16 + lc;

    f16x8 bfrag[KSTEPS];
    #pragma unroll
    for (int half = 0; half < 2; ++half) {
        const int fb = half * 32 + q * 8;        // 8 consecutive freqs
        #pragma unroll
        for (int jq = 0; jq < 2; ++jq) {         // two quads of 4 freqs
            // 12 consecutive floats per array = 4 freqs x 3 kernels, 16B-aligned
            const size_t off = ((size_t)bin * NFREQ + fb + jq * 4) * NKER;
            float4 m4[3], k4[3], w4[3];
            #pragma unroll
            for (int i = 0; i < 3; ++i) {
                m4[i] = ((const float4*)(mu + off))[i];
                k4[i] = ((const float4*)(kappa + off))[i];
                w4[i] = ((const float4*)(weight + off))[i];
            }
            const float* mv = (const float*)m4;
            const float* kv = (const float*)k4;
            const float* wv = (const float*)w4;

            #pragma unroll
            for (int jj = 0; jj < 4; ++jj) {
                const int j = jq * 4 + jj;
                const float rf = refang[fb + j];
                float ach[NCH];
                #pragma unroll
                for (int c = 0; c < NCH; ++c) ach[c] = 0.f;

                #pragma unroll
                for (int k = 0; k < NKER; ++k) {
                    const float me  = mv[3 * jj + k] + rf;
                    const float kap = kv[3 * jj + k];
                    const float w   = wv[3 * jj + k];
                    const float wek = w * __expf(-kap);
                    float s1, c1;
                    __sincosf(me, &s1, &c1);
                    const float h = 0.5f * kap, h2 = h * h;

                    float Im[MHARM + 1];
                    float tm = 1.f;               // h^m / m!
                    #pragma unroll
                    for (int m = 0; m <= MHARM; ++m) {
                        float t = tm, s = tm;
                        #pragma unroll
                        for (int u = 1; u <= 4; ++u) { t *= h2 / (float)(u * (m + u)); s += t; }
                        Im[m] = s;
                        tm *= h / (float)(m + 1);
                    }

                    ach[0] = fmaf(wek, Im[0], ach[0]);
                    float cp = 1.f, sp = 0.f, cc = c1, sc = s1;
                    #pragma unroll
                    for (int m = 1; m <= MHARM; ++m) {
                        const float gm = 2.f * wek * Im[m];
                        ach[2 * m - 1] = fmaf(gm, cc, ach[2 * m - 1]);
                        ach[2 * m]     = fmaf(gm, sc, ach[2 * m]);
                        const float cn = fmaf(2.f * c1, cc, -cp);
                        const float sn = fmaf(2.f * c1, sc, -sp);
                        cp = cc; sp = sc; cc = cn; sc = sn;
                    }
                }
                #pragma unroll
                for (int c = 0; c < NCH; ++c)
                    bfrag[c * 2 + half][j] = (_Float16)ach[c];
            }
        }
    }

    __syncthreads();

    // ---------------- GEMM: 14 K-steps x 4 row-chunks, B in VGPRs ----------
    f32x4 acc[4] = {};
    const f16x8* ap = (const f16x8*)Afrag + SWZ(lane);   // swizzled, conflict-free
    #pragma unroll
    for (int kt = 0; kt < KSTEPS; ++kt) {
        #pragma unroll
        for (int c = 0; c < 4; ++c) {
            const f16x8 a = ap[c * (KSTEPS * 64) + kt * 64];
            acc[c] = __builtin_amdgcn_mfma_f32_16x16x32_f16(a, bfrag[kt], acc[c], 0, 0, 0);
        }
    }

    // C/D layout: col = lane&15, row = (lane>>4)*4 + reg
    const int col = g * 16 + lc;
    const float bb = bias[col];
    #pragma unroll
    for (int c = 0; c < 4; ++c) {
        #pragma unroll
        for (int jj = 0; jj < 4; ++jj)
            out[(size_t)(row0 + c * 16 + q * 4 + jj) * NBINS + col] = acc[c][jj] + bb;
    }
}

// ---------------------------------------------------------------------------
extern "C" void kernel_launch(void* const* d_in, const int* in_sizes, int n_in,
                              void* d_out, int out_size, void* d_ws, size_t ws_size,
                              hipStream_t stream) {
    const float* K      = (const float*)d_in[0];
    const float* refang = (const float*)d_in[1];
    const float* mu     = (const float*)d_in[2];
    const float* kappa  = (const float*)d_in[3];
    const float* weight = (const float*)d_in[4];
    const float* bias   = (const float*)d_in[5];
    float* out = (float*)d_out;

    (void)d_ws; (void)ws_size; (void)in_sizes; (void)n_in; (void)out_size;

    fused_all<<<(NKEYS / BM) * 2, GT, 0, stream>>>(
        K, refang, mu, kappa, weight, bias, out);
}